// Round 1
// baseline (2398.976 us; speedup 1.0000x reference)
//
#include <hip/hip_runtime.h>
#include <hip/hip_fp16.h>
#include <math.h>
#include <stdint.h>

typedef _Float16 f16;
typedef _Float16 h8 __attribute__((ext_vector_type(8)));
typedef float f4 __attribute__((ext_vector_type(4)));

#define B_N   16384
#define KPAD  192     // padded input dim (161 -> 192)
#define TSTEPS 48

#define MFMA(a,b,c) __builtin_amdgcn_mfma_f32_16x16x32_f16((a),(b),(c),0,0,0)

__device__ __forceinline__ float gelu_f(float x) {
  return 0.5f * x * (1.0f + erff(x * 0.7071067811865475f));
}

__device__ __forceinline__ float tanh_f(float x) {
  x = fminf(fmaxf(x, -15.f), 15.f);
  float a = exp2f(x * 2.885390081777927f);   // e^{2x}
  return (a - 1.f) / (a + 1.f);
}

// ---------------- weight prep: transpose + cast to fp16, pad K ----------------
// dst[n][kpad] = (k < K) ? src[k][n] : 0
__global__ void prep_t(const float* __restrict__ src, f16* __restrict__ dst,
                       int K, int N, int Kpad) {
  int idx = blockIdx.x * 256 + threadIdx.x;
  if (idx >= N * Kpad) return;
  int n = idx / Kpad, k = idx - n * Kpad;
  float v = (k < K) ? src[k * N + n] : 0.f;
  dst[idx] = (f16)v;
}

// ---------------- feature kernel: fourier + hashgrid + z -> fp16 [B][192] ----
__global__ void feat_kernel(const float* __restrict__ x, const float* __restrict__ z,
                            const float* __restrict__ tables, const int* __restrict__ res,
                            const float* __restrict__ freqs, f16* __restrict__ featsH) {
  __shared__ f16 rowbuf[64][194];   // +2 pad -> 388B row stride (odd dwords, conflict-free)
  const int t = threadIdx.x;        // 64 threads
  const int b = blockIdx.x;
  const int i = b * 64 + t;

  float xv = x[i];
  float xn = fminf(fmaxf(xv, 0.f), 1.f);
  f16* dst = rowbuf[t];
  dst[0] = (f16)xn;
  float w2pi = 6.283185307179586f * xn;
  #pragma unroll
  for (int k = 0; k < 32; ++k) {
    float a = w2pi * freqs[k];
    float s, c;
    sincosf(a, &s, &c);
    dst[1 + k]  = (f16)s;
    dst[33 + k] = (f16)c;
  }
  #pragma unroll
  for (int l = 0; l < 8; ++l) {
    int R = res[l];
    int Rm1 = R - 1;
    float tt = xn * (float)Rm1;
    int i0 = (int)tt;                 // tt >= 0 -> trunc == floor
    int i1 = min(i0 + 1, Rm1);
    float w = tt - (float)i0;
    uint32_t lt = (uint32_t)(l * 19349663);
    uint32_t h0 = (((uint32_t)i0 * 73856093u) ^ lt) & 16383u;
    uint32_t h1 = (((uint32_t)i1 * 73856093u) ^ lt) & 16383u;
    const float* e0 = tables + ((size_t)l * 16384 + h0) * 8;
    const float* e1 = tables + ((size_t)l * 16384 + h1) * 8;
    #pragma unroll
    for (int e = 0; e < 8; ++e) {
      float v = e0[e] * (1.f - w) + e1[e] * w;
      dst[65 + l * 8 + e] = (f16)v;
    }
  }
  #pragma unroll
  for (int j = 0; j < 32; ++j) dst[129 + j] = (f16)z[(size_t)i * 32 + j];
  #pragma unroll
  for (int j = 161; j < 192; ++j) dst[j] = (f16)0.f;

  __syncthreads();
  // coalesced copy to global (plain row-major [64][192] fp16)
  uint32_t* dg = (uint32_t*)(featsH + (size_t)b * 64 * KPAD);
  for (int idx = t; idx < 64 * 96; idx += 64) {
    int row = idx / 96, o = idx - row * 96;
    dg[idx] = ((const uint32_t*)&rowbuf[row][0])[o];
  }
}

// ---------------- main fused kernel ----------------
// 256 blocks x 512 threads (8 waves). Block owns 64 rows.
// Wave-grid 1Mx8N: wave wn covers cols [64*wn,+64) in FF space, [32*wn,+32) in HID space.
// LDS: hB = fp16 h tile [64][256] (row stride 512B), uB = fp16 u tile [64][512] (stride 1024B).
// Swizzle: element (row,k) stored at row*RS + ((2k) ^ ((row&7)<<4)).
__global__ __launch_bounds__(512, 2) void fractal_main(
    const f16* __restrict__ featsH,
    const f16* __restrict__ W1t, const f16* __restrict__ W2t,
    const f16* __restrict__ Wf1t, const f16* __restrict__ Wf2t,
    const f16* __restrict__ Wot,
    const float* __restrict__ b1, const float* __restrict__ b2,
    const float* __restrict__ bf1, const float* __restrict__ bf2,
    const float* __restrict__ bo,
    float* __restrict__ out) {
  extern __shared__ char smem[];
  char* hB = smem;            // 32768 B
  char* uB = smem + 32768;    // 65536 B (feats staging reuses: [64][384B])

  const int tid = threadIdx.x;
  const int wn  = tid >> 6;
  const int ln  = tid & 63;
  const int r   = ln & 15;
  const int g   = ln >> 4;
  const int sw  = (r & 7) << 4;          // swizzle for A-reads (row = 16*mf + r)
  const int g16 = g * 16;
  const int row0 = blockIdx.x * 64;

  float b1r[2], b2r[2], bf2r[2], bor[2], bf1r[4];
  #pragma unroll
  for (int nf = 0; nf < 2; ++nf) {
    int c = 32 * wn + 16 * nf + r;
    b1r[nf] = b1[c]; b2r[nf] = b2[c]; bf2r[nf] = bf2[c]; bor[nf] = bo[c];
  }
  #pragma unroll
  for (int nf = 0; nf < 4; ++nf) bf1r[nf] = bf1[64 * wn + 16 * nf + r];

  // ---- stage feats tile into uB (swizzled, row stride 384B) ----
  {
    const char* src = (const char*)featsH + (size_t)row0 * 384;
    for (int i = tid; i < 6144; i += 512) {
      int row = i / 96;
      int off = (i - row * 96) * 4;
      uint32_t v = *(const uint32_t*)(src + (size_t)i * 4);
      *(uint32_t*)(uB + row * 384 + (off ^ ((row & 7) << 4))) = v;
    }
  }
  __syncthreads();

  f4 m[4][2];   // master h (f32), rows 16*mf+g*4+j, cols 32*wn+16*nf+r
  const f4 zf = {0.f, 0.f, 0.f, 0.f};

  // ---- layer 1: feats @ W1 ----
  {
    f4 acc[4][2];
    #pragma unroll
    for (int mf = 0; mf < 4; ++mf)
      #pragma unroll
      for (int nf = 0; nf < 2; ++nf) acc[mf][nf] = zf;
    #pragma unroll
    for (int kk = 0; kk < 6; ++kk) {
      h8 a[4], bb[2];
      #pragma unroll
      for (int mf = 0; mf < 4; ++mf) {
        int row = 16 * mf + r;
        a[mf] = *(const h8*)(uB + row * 384 + ((kk * 64 + g16) ^ sw));
      }
      #pragma unroll
      for (int nf = 0; nf < 2; ++nf)
        bb[nf] = *(const h8*)(W1t + (32 * wn + 16 * nf + r) * 192 + kk * 32 + g * 8);
      #pragma unroll
      for (int mf = 0; mf < 4; ++mf)
        #pragma unroll
        for (int nf = 0; nf < 2; ++nf)
          acc[mf][nf] = MFMA(a[mf], bb[nf], acc[mf][nf]);
    }
    #pragma unroll
    for (int mf = 0; mf < 4; ++mf)
      #pragma unroll
      for (int nf = 0; nf < 2; ++nf)
        #pragma unroll
        for (int j = 0; j < 4; ++j)
          m[mf][nf][j] = gelu_f(acc[mf][nf][j] + b1r[nf]);
  }
  // write h to hB
  #pragma unroll
  for (int mf = 0; mf < 4; ++mf)
    #pragma unroll
    for (int nf = 0; nf < 2; ++nf)
      #pragma unroll
      for (int j = 0; j < 4; ++j) {
        int row = 16 * mf + g * 4 + j;
        int col = 32 * wn + 16 * nf + r;
        *(f16*)(hB + row * 512 + ((col * 2) ^ ((row & 7) << 4))) = (f16)m[mf][nf][j];
      }
  __syncthreads();

  // ---- layer 2: h @ W2 ----
  {
    f4 acc[4][2];
    #pragma unroll
    for (int mf = 0; mf < 4; ++mf)
      #pragma unroll
      for (int nf = 0; nf < 2; ++nf) acc[mf][nf] = zf;
    #pragma unroll
    for (int kk = 0; kk < 8; ++kk) {
      h8 a[4], bb[2];
      #pragma unroll
      for (int mf = 0; mf < 4; ++mf) {
        int row = 16 * mf + r;
        a[mf] = *(const h8*)(hB + row * 512 + ((kk * 64 + g16) ^ sw));
      }
      #pragma unroll
      for (int nf = 0; nf < 2; ++nf)
        bb[nf] = *(const h8*)(W2t + (32 * wn + 16 * nf + r) * 256 + kk * 32 + g * 8);
      #pragma unroll
      for (int mf = 0; mf < 4; ++mf)
        #pragma unroll
        for (int nf = 0; nf < 2; ++nf)
          acc[mf][nf] = MFMA(a[mf], bb[nf], acc[mf][nf]);
    }
    #pragma unroll
    for (int mf = 0; mf < 4; ++mf)
      #pragma unroll
      for (int nf = 0; nf < 2; ++nf)
        #pragma unroll
        for (int j = 0; j < 4; ++j)
          m[mf][nf][j] = gelu_f(acc[mf][nf][j] + b2r[nf]);
  }
  __syncthreads();   // all waves done reading old hB
  #pragma unroll
  for (int mf = 0; mf < 4; ++mf)
    #pragma unroll
    for (int nf = 0; nf < 2; ++nf)
      #pragma unroll
      for (int j = 0; j < 4; ++j) {
        int row = 16 * mf + g * 4 + j;
        int col = 32 * wn + 16 * nf + r;
        *(f16*)(hB + row * 512 + ((col * 2) ^ ((row & 7) << 4))) = (f16)m[mf][nf][j];
      }
  __syncthreads();

  // ---- 48 fractal steps ----
  for (int t = 0; t < TSTEPS; ++t) {
    // GEMM1: u1 = h @ Wf1  (N=512), wave cols [64*wn,+64)
    f4 a1[4][4];
    #pragma unroll
    for (int mf = 0; mf < 4; ++mf)
      #pragma unroll
      for (int nf = 0; nf < 4; ++nf) a1[mf][nf] = zf;
    #pragma unroll
    for (int kk = 0; kk < 8; ++kk) {
      h8 a[4], bb[4];
      #pragma unroll
      for (int mf = 0; mf < 4; ++mf) {
        int row = 16 * mf + r;
        a[mf] = *(const h8*)(hB + row * 512 + ((kk * 64 + g16) ^ sw));
      }
      #pragma unroll
      for (int nf = 0; nf < 4; ++nf)
        bb[nf] = *(const h8*)(Wf1t + (64 * wn + 16 * nf + r) * 256 + kk * 32 + g * 8);
      #pragma unroll
      for (int mf = 0; mf < 4; ++mf)
        #pragma unroll
        for (int nf = 0; nf < 4; ++nf)
          a1[mf][nf] = MFMA(a[mf], bb[nf], a1[mf][nf]);
    }
    // epilogue: gelu -> uB (fp16, swizzled)
    #pragma unroll
    for (int mf = 0; mf < 4; ++mf)
      #pragma unroll
      for (int nf = 0; nf < 4; ++nf)
        #pragma unroll
        for (int j = 0; j < 4; ++j) {
          float gv = gelu_f(a1[mf][nf][j] + bf1r[nf]);
          int row = 16 * mf + g * 4 + j;
          int col = 64 * wn + 16 * nf + r;
          *(f16*)(uB + row * 1024 + ((col * 2) ^ ((row & 7) << 4))) = (f16)gv;
        }
    __syncthreads();

    // GEMM2: u2 = gelu(u1) @ Wf2  (N=256, K=512), wave cols [32*wn,+32)
    f4 a2[4][2];
    #pragma unroll
    for (int mf = 0; mf < 4; ++mf)
      #pragma unroll
      for (int nf = 0; nf < 2; ++nf) a2[mf][nf] = zf;
    #pragma unroll
    for (int kk = 0; kk < 16; ++kk) {
      h8 a[4], bb[2];
      #pragma unroll
      for (int mf = 0; mf < 4; ++mf) {
        int row = 16 * mf + r;
        a[mf] = *(const h8*)(uB + row * 1024 + ((kk * 64 + g16) ^ sw));
      }
      #pragma unroll
      for (int nf = 0; nf < 2; ++nf)
        bb[nf] = *(const h8*)(Wf2t + (32 * wn + 16 * nf + r) * 512 + kk * 32 + g * 8);
      #pragma unroll
      for (int mf = 0; mf < 4; ++mf)
        #pragma unroll
        for (int nf = 0; nf < 2; ++nf)
          a2[mf][nf] = MFMA(a[mf], bb[nf], a2[mf][nf]);
    }
    // epilogue: tanh, mix, write hB
    #pragma unroll
    for (int mf = 0; mf < 4; ++mf)
      #pragma unroll
      for (int nf = 0; nf < 2; ++nf)
        #pragma unroll
        for (int j = 0; j < 4; ++j) {
          float u = tanh_f(a2[mf][nf][j] + bf2r[nf]);
          float hn = 0.5f * (m[mf][nf][j] + u);
          m[mf][nf][j] = hn;
          int row = 16 * mf + g * 4 + j;
          int col = 32 * wn + 16 * nf + r;
          *(f16*)(hB + row * 512 + ((col * 2) ^ ((row & 7) << 4))) = (f16)hn;
        }
    __syncthreads();
  }

  // ---- final: out = h @ Wo + bo ----
  {
    f4 acc[4][2];
    #pragma unroll
    for (int mf = 0; mf < 4; ++mf)
      #pragma unroll
      for (int nf = 0; nf < 2; ++nf) acc[mf][nf] = zf;
    #pragma unroll
    for (int kk = 0; kk < 8; ++kk) {
      h8 a[4], bb[2];
      #pragma unroll
      for (int mf = 0; mf < 4; ++mf) {
        int row = 16 * mf + r;
        a[mf] = *(const h8*)(hB + row * 512 + ((kk * 64 + g16) ^ sw));
      }
      #pragma unroll
      for (int nf = 0; nf < 2; ++nf)
        bb[nf] = *(const h8*)(Wot + (32 * wn + 16 * nf + r) * 256 + kk * 32 + g * 8);
      #pragma unroll
      for (int mf = 0; mf < 4; ++mf)
        #pragma unroll
        for (int nf = 0; nf < 2; ++nf)
          acc[mf][nf] = MFMA(a[mf], bb[nf], acc[mf][nf]);
    }
    #pragma unroll
    for (int mf = 0; mf < 4; ++mf)
      #pragma unroll
      for (int nf = 0; nf < 2; ++nf)
        #pragma unroll
        for (int j = 0; j < 4; ++j) {
          int row = row0 + 16 * mf + g * 4 + j;
          int col = 32 * wn + 16 * nf + r;
          out[(size_t)row * 256 + col] = acc[mf][nf][j] + bor[nf];
        }
  }
}

// ---------------- host launch ----------------
extern "C" void kernel_launch(void* const* d_in, const int* in_sizes, int n_in,
                              void* d_out, int out_size, void* d_ws, size_t ws_size,
                              hipStream_t stream) {
  const float* x      = (const float*)d_in[0];
  const float* z      = (const float*)d_in[1];
  const float* tables = (const float*)d_in[2];
  const float* W1     = (const float*)d_in[3];
  const float* b1     = (const float*)d_in[4];
  const float* W2     = (const float*)d_in[5];
  const float* b2     = (const float*)d_in[6];
  const float* Wf1    = (const float*)d_in[7];
  const float* bf1    = (const float*)d_in[8];
  const float* Wf2    = (const float*)d_in[9];
  const float* bf2    = (const float*)d_in[10];
  const float* Wo     = (const float*)d_in[11];
  const float* bo     = (const float*)d_in[12];
  const int*   res    = (const int*)d_in[13];
  const float* freqs  = (const float*)d_in[14];
  float* out = (float*)d_out;

  char* ws = (char*)d_ws;
  f16* featsH = (f16*)(ws);                 // 16384*192*2 = 6291456
  f16* W1t    = (f16*)(ws + 6291456);       // 256*192*2   = 98304
  f16* W2t    = (f16*)(ws + 6389760);       // 256*256*2   = 131072
  f16* Wf1t   = (f16*)(ws + 6520832);       // 512*256*2   = 262144
  f16* Wf2t   = (f16*)(ws + 6782976);       // 256*512*2   = 262144
  f16* Wot    = (f16*)(ws + 7045120);       // 256*256*2   = 131072

  prep_t<<<(256 * 192 + 255) / 256, 256, 0, stream>>>(W1, W1t, 161, 256, 192);
  prep_t<<<(256 * 256 + 255) / 256, 256, 0, stream>>>(W2, W2t, 256, 256, 256);
  prep_t<<<(512 * 256 + 255) / 256, 256, 0, stream>>>(Wf1, Wf1t, 256, 512, 256);
  prep_t<<<(256 * 512 + 255) / 256, 256, 0, stream>>>(Wf2, Wf2t, 512, 256, 512);
  prep_t<<<(256 * 256 + 255) / 256, 256, 0, stream>>>(Wo, Wot, 256, 256, 256);
  feat_kernel<<<256, 64, 0, stream>>>(x, z, tables, res, freqs, featsH);

  (void)hipFuncSetAttribute((const void*)fractal_main,
                            hipFuncAttributeMaxDynamicSharedMemorySize, 98304);
  fractal_main<<<256, 512, 98304, stream>>>(featsH, W1t, W2t, Wf1t, Wf2t, Wot,
                                            b1, b2, bf1, bf2, bo, out);
}

// Round 3
// 2219.740 us; speedup vs baseline: 1.0807x; 1.0807x over previous
//
#include <hip/hip_runtime.h>
#include <hip/hip_fp16.h>
#include <math.h>
#include <stdint.h>

typedef _Float16 f16;
typedef _Float16 h8 __attribute__((ext_vector_type(8)));
typedef float f4 __attribute__((ext_vector_type(4)));

#define TSTEPS 48

#define MFMA(a,b,c) __builtin_amdgcn_mfma_f32_16x16x32_f16((a),(b),(c),0,0,0)

// branch-free gelu via A&S 7.1.26 erf approx (max abs err 1.5e-7 << f16 rounding)
__device__ __forceinline__ float gelu_f(float x) {
  float ax = fabsf(x) * 0.7071067811865475f;
  float t = __builtin_amdgcn_rcpf(1.0f + 0.3275911f * ax);
  float poly = t * (0.254829592f + t * (-0.284496736f + t * (1.421413741f +
               t * (-1.453152027f + t * 1.061405429f))));
  float e = exp2f(-ax * ax * 1.4426950408889634f);
  float er = copysignf(1.0f - poly * e, x);
  return 0.5f * x * (1.0f + er);
}

// tanh = 1 - 2/(e^{2x}+1); exp2 overflow/underflow gives correct +-1 limits
__device__ __forceinline__ float tanh_f(float x) {
  float e = exp2f(x * 2.885390081777927f);   // e^{2x}
  return 1.0f - 2.0f * __builtin_amdgcn_rcpf(e + 1.0f);
}

// ---------------- weight prep: k-slice stream  dst[(kk*N+n)*32+w] = src[(kk*32+w)*N+n]
__global__ void prep_ws(const float* __restrict__ src, f16* __restrict__ dst,
                        int Kreal, int N, int total) {
  int idx = blockIdx.x * 256 + threadIdx.x;
  if (idx >= total) return;
  int w = idx & 31;
  int n = (idx >> 5) % N;
  int kk = idx / (N * 32);
  int k = kk * 32 + w;
  dst[idx] = (f16)((k < Kreal) ? src[k * N + n] : 0.f);
}

// ---------------- feature kernel: fourier + hashgrid + z -> fp16 [B][192] ----
__global__ void feat_kernel(const float* __restrict__ x, const float* __restrict__ z,
                            const float* __restrict__ tables, const int* __restrict__ res,
                            const float* __restrict__ freqs, f16* __restrict__ featsH) {
  __shared__ f16 rowbuf[64][194];
  const int t = threadIdx.x;        // 64 threads
  const int b = blockIdx.x;
  const int i = b * 64 + t;

  float xv = x[i];
  float xn = fminf(fmaxf(xv, 0.f), 1.f);
  f16* dst = rowbuf[t];
  dst[0] = (f16)xn;
  float w2pi = 6.283185307179586f * xn;
  #pragma unroll
  for (int k = 0; k < 32; ++k) {
    float a = w2pi * freqs[k];
    float s, c;
    sincosf(a, &s, &c);
    dst[1 + k]  = (f16)s;
    dst[33 + k] = (f16)c;
  }
  #pragma unroll
  for (int l = 0; l < 8; ++l) {
    int R = res[l];
    int Rm1 = R - 1;
    float tt = xn * (float)Rm1;
    int i0 = (int)tt;
    int i1 = min(i0 + 1, Rm1);
    float w = tt - (float)i0;
    uint32_t lt = (uint32_t)(l * 19349663);
    uint32_t h0 = (((uint32_t)i0 * 73856093u) ^ lt) & 16383u;
    uint32_t h1 = (((uint32_t)i1 * 73856093u) ^ lt) & 16383u;
    const float* e0 = tables + ((size_t)l * 16384 + h0) * 8;
    const float* e1 = tables + ((size_t)l * 16384 + h1) * 8;
    #pragma unroll
    for (int e = 0; e < 8; ++e) {
      float v = e0[e] * (1.f - w) + e1[e] * w;
      dst[65 + l * 8 + e] = (f16)v;
    }
  }
  #pragma unroll
  for (int j = 0; j < 32; ++j) dst[129 + j] = (f16)z[(size_t)i * 32 + j];
  #pragma unroll
  for (int j = 161; j < 192; ++j) dst[j] = (f16)0.f;

  __syncthreads();
  uint32_t* dg = (uint32_t*)(featsH + (size_t)b * 64 * 192);
  for (int idx = t; idx < 64 * 96; idx += 64) {
    int row = idx / 96, o = idx - row * 96;
    dg[idx] = ((const uint32_t*)&rowbuf[row][0])[o];
  }
}

// ---------------- main fused kernel ----------------
// 256 blocks x 512 threads (8 waves). Block owns 64 rows.
// LDS: hB [0,32K) fp16 h tile [64][256] stride 512B (XOR-swizzled)
//      uB [32K,96K) fp16 u tile [64][512] stride 1024B (feats staging reuses)
// B-operands: direct global loads from k-slice streams (contiguous 1KB/wave/frag,
// L2-resident) — no LDS staging (no cross-wave reuse exists).
__global__ __launch_bounds__(512, 2) void fractal_main(
    const f16* __restrict__ featsH,
    const f16* __restrict__ W1s, const f16* __restrict__ W2s,
    const f16* __restrict__ Wos,
    const f16* __restrict__ Wf1s, const f16* __restrict__ Wf2s,
    const float* __restrict__ b1, const float* __restrict__ b2,
    const float* __restrict__ bf1, const float* __restrict__ bf2,
    const float* __restrict__ bo,
    float* __restrict__ out) {
  extern __shared__ char smem[];
  char* hB = smem;
  char* uB = smem + 32768;

  const int tid = threadIdx.x;
  const int wn  = tid >> 6;
  const int ln  = tid & 63;
  const int r   = ln & 15;
  const int g   = ln >> 4;
  const int sw  = (r & 7) << 4;
  const int g16 = g * 16;
  const int row0 = blockIdx.x * 64;

  float b1r[2], b2r[2], bf2r[2], bor[2], bf1r[4];
  #pragma unroll
  for (int nf = 0; nf < 2; ++nf) {
    int c = 32 * wn + 16 * nf + r;
    b1r[nf] = b1[c]; b2r[nf] = b2[c]; bf2r[nf] = bf2[c]; bor[nf] = bo[c];
  }
  #pragma unroll
  for (int nf = 0; nf < 4; ++nf) bf1r[nf] = bf1[64 * wn + 16 * nf + r];

  // ---- stage feats tile into uB (swizzled, row stride 384B) ----
  {
    const char* src = (const char*)featsH + (size_t)row0 * 384;
    for (int i = tid; i < 6144; i += 512) {
      int row = i / 96;
      int off = (i - row * 96) * 4;
      uint32_t v = *(const uint32_t*)(src + (size_t)i * 4);
      *(uint32_t*)(uB + row * 384 + (off ^ ((row & 7) << 4))) = v;
    }
  }
  __syncthreads();

  f4 m[4][2];
  const f4 zf = {0.f, 0.f, 0.f, 0.f};

  // ---- layer 1: feats @ W1 ----
  {
    f4 acc[4][2];
    #pragma unroll
    for (int mf = 0; mf < 4; ++mf)
      #pragma unroll
      for (int nf = 0; nf < 2; ++nf) acc[mf][nf] = zf;
    #pragma unroll
    for (int kk = 0; kk < 6; ++kk) {
      h8 a[4], bb[2];
      #pragma unroll
      for (int mf = 0; mf < 4; ++mf)
        a[mf] = *(const h8*)(uB + (16 * mf + r) * 384 + ((kk * 64 + g16) ^ sw));
      #pragma unroll
      for (int nf = 0; nf < 2; ++nf)
        bb[nf] = *(const h8*)(W1s + ((kk * 256 + 32 * wn + 16 * nf + r) << 5) + g * 8);
      #pragma unroll
      for (int mf = 0; mf < 4; ++mf)
        #pragma unroll
        for (int nf = 0; nf < 2; ++nf)
          acc[mf][nf] = MFMA(a[mf], bb[nf], acc[mf][nf]);
    }
    #pragma unroll
    for (int mf = 0; mf < 4; ++mf)
      #pragma unroll
      for (int nf = 0; nf < 2; ++nf)
        #pragma unroll
        for (int j = 0; j < 4; ++j)
          m[mf][nf][j] = gelu_f(acc[mf][nf][j] + b1r[nf]);
  }
  #pragma unroll
  for (int mf = 0; mf < 4; ++mf)
    #pragma unroll
    for (int nf = 0; nf < 2; ++nf)
      #pragma unroll
      for (int j = 0; j < 4; ++j) {
        int row = 16 * mf + g * 4 + j;
        int col = 32 * wn + 16 * nf + r;
        *(f16*)(hB + row * 512 + ((col * 2) ^ ((row & 7) << 4))) = (f16)m[mf][nf][j];
      }
  __syncthreads();

  // ---- layer 2: h @ W2 ----
  {
    f4 acc[4][2];
    #pragma unroll
    for (int mf = 0; mf < 4; ++mf)
      #pragma unroll
      for (int nf = 0; nf < 2; ++nf) acc[mf][nf] = zf;
    #pragma unroll
    for (int kk = 0; kk < 8; ++kk) {
      h8 a[4], bb[2];
      #pragma unroll
      for (int mf = 0; mf < 4; ++mf)
        a[mf] = *(const h8*)(hB + (16 * mf + r) * 512 + ((kk * 64 + g16) ^ sw));
      #pragma unroll
      for (int nf = 0; nf < 2; ++nf)
        bb[nf] = *(const h8*)(W2s + ((kk * 256 + 32 * wn + 16 * nf + r) << 5) + g * 8);
      #pragma unroll
      for (int mf = 0; mf < 4; ++mf)
        #pragma unroll
        for (int nf = 0; nf < 2; ++nf)
          acc[mf][nf] = MFMA(a[mf], bb[nf], acc[mf][nf]);
    }
    #pragma unroll
    for (int mf = 0; mf < 4; ++mf)
      #pragma unroll
      for (int nf = 0; nf < 2; ++nf)
        #pragma unroll
        for (int j = 0; j < 4; ++j)
          m[mf][nf][j] = gelu_f(acc[mf][nf][j] + b2r[nf]);
  }
  __syncthreads();   // all waves done reading old hB
  #pragma unroll
  for (int mf = 0; mf < 4; ++mf)
    #pragma unroll
    for (int nf = 0; nf < 2; ++nf)
      #pragma unroll
      for (int j = 0; j < 4; ++j) {
        int row = 16 * mf + g * 4 + j;
        int col = 32 * wn + 16 * nf + r;
        *(f16*)(hB + row * 512 + ((col * 2) ^ ((row & 7) << 4))) = (f16)m[mf][nf][j];
      }
  __syncthreads();

  // ---- 48 fractal steps, 2 barriers per step ----
  for (int t = 0; t < TSTEPS; ++t) {
    // GEMM1: u = h @ Wf1 (N=512), wave cols [64*wn,+64)
    f4 a1[4][4];
    #pragma unroll
    for (int mf = 0; mf < 4; ++mf)
      #pragma unroll
      for (int nf = 0; nf < 4; ++nf) a1[mf][nf] = zf;
    #pragma unroll
    for (int kk = 0; kk < 8; ++kk) {
      h8 a[4], bb[4];
      #pragma unroll
      for (int mf = 0; mf < 4; ++mf)
        a[mf] = *(const h8*)(hB + (16 * mf + r) * 512 + ((kk * 64 + g16) ^ sw));
      #pragma unroll
      for (int nf = 0; nf < 4; ++nf)
        bb[nf] = *(const h8*)(Wf1s + ((kk * 512 + 64 * wn + 16 * nf + r) << 5) + g * 8);
      #pragma unroll
      for (int mf = 0; mf < 4; ++mf)
        #pragma unroll
        for (int nf = 0; nf < 4; ++nf)
          a1[mf][nf] = MFMA(a[mf], bb[nf], a1[mf][nf]);
    }
    // epilogue: gelu -> uB
    #pragma unroll
    for (int mf = 0; mf < 4; ++mf)
      #pragma unroll
      for (int nf = 0; nf < 4; ++nf)
        #pragma unroll
        for (int j = 0; j < 4; ++j) {
          float gv = gelu_f(a1[mf][nf][j] + bf1r[nf]);
          int row = 16 * mf + g * 4 + j;
          int col = 64 * wn + 16 * nf + r;
          *(f16*)(uB + row * 1024 + ((col * 2) ^ ((row & 7) << 4))) = (f16)gv;
        }
    __syncthreads();

    // GEMM2: h' = tanh(u @ Wf2) (N=256, K=512), wave cols [32*wn,+32)
    f4 a2[4][2];
    #pragma unroll
    for (int mf = 0; mf < 4; ++mf)
      #pragma unroll
      for (int nf = 0; nf < 2; ++nf) a2[mf][nf] = zf;
    #pragma unroll
    for (int kk = 0; kk < 16; ++kk) {
      h8 a[4], bb[2];
      #pragma unroll
      for (int mf = 0; mf < 4; ++mf)
        a[mf] = *(const h8*)(uB + (16 * mf + r) * 1024 + ((kk * 64 + g16) ^ sw));
      #pragma unroll
      for (int nf = 0; nf < 2; ++nf)
        bb[nf] = *(const h8*)(Wf2s + ((kk * 256 + 32 * wn + 16 * nf + r) << 5) + g * 8);
      #pragma unroll
      for (int mf = 0; mf < 4; ++mf)
        #pragma unroll
        for (int nf = 0; nf < 2; ++nf)
          a2[mf][nf] = MFMA(a[mf], bb[nf], a2[mf][nf]);
    }
    // epilogue: tanh, mix, write hB
    #pragma unroll
    for (int mf = 0; mf < 4; ++mf)
      #pragma unroll
      for (int nf = 0; nf < 2; ++nf)
        #pragma unroll
        for (int j = 0; j < 4; ++j) {
          float u = tanh_f(a2[mf][nf][j] + bf2r[nf]);
          float hn = 0.5f * (m[mf][nf][j] + u);
          m[mf][nf][j] = hn;
          int row = 16 * mf + g * 4 + j;
          int col = 32 * wn + 16 * nf + r;
          *(f16*)(hB + row * 512 + ((col * 2) ^ ((row & 7) << 4))) = (f16)hn;
        }
    __syncthreads();
  }

  // ---- final: out = h @ Wo + bo ----
  {
    f4 acc[4][2];
    #pragma unroll
    for (int mf = 0; mf < 4; ++mf)
      #pragma unroll
      for (int nf = 0; nf < 2; ++nf) acc[mf][nf] = zf;
    #pragma unroll
    for (int kk = 0; kk < 8; ++kk) {
      h8 a[4], bb[2];
      #pragma unroll
      for (int mf = 0; mf < 4; ++mf)
        a[mf] = *(const h8*)(hB + (16 * mf + r) * 512 + ((kk * 64 + g16) ^ sw));
      #pragma unroll
      for (int nf = 0; nf < 2; ++nf)
        bb[nf] = *(const h8*)(Wos + ((kk * 256 + 32 * wn + 16 * nf + r) << 5) + g * 8);
      #pragma unroll
      for (int mf = 0; mf < 4; ++mf)
        #pragma unroll
        for (int nf = 0; nf < 2; ++nf)
          acc[mf][nf] = MFMA(a[mf], bb[nf], acc[mf][nf]);
    }
    #pragma unroll
    for (int mf = 0; mf < 4; ++mf)
      #pragma unroll
      for (int nf = 0; nf < 2; ++nf)
        #pragma unroll
        for (int j = 0; j < 4; ++j) {
          int row = row0 + 16 * mf + g * 4 + j;
          int col = 32 * wn + 16 * nf + r;
          out[(size_t)row * 256 + col] = acc[mf][nf][j] + bor[nf];
        }
  }
}

// ---------------- host launch ----------------
extern "C" void kernel_launch(void* const* d_in, const int* in_sizes, int n_in,
                              void* d_out, int out_size, void* d_ws, size_t ws_size,
                              hipStream_t stream) {
  const float* x      = (const float*)d_in[0];
  const float* z      = (const float*)d_in[1];
  const float* tables = (const float*)d_in[2];
  const float* W1     = (const float*)d_in[3];
  const float* b1     = (const float*)d_in[4];
  const float* W2     = (const float*)d_in[5];
  const float* b2     = (const float*)d_in[6];
  const float* Wf1    = (const float*)d_in[7];
  const float* bf1    = (const float*)d_in[8];
  const float* Wf2    = (const float*)d_in[9];
  const float* bf2    = (const float*)d_in[10];
  const float* Wo     = (const float*)d_in[11];
  const float* bo     = (const float*)d_in[12];
  const int*   res    = (const int*)d_in[13];
  const float* freqs  = (const float*)d_in[14];
  float* out = (float*)d_out;

  char* ws = (char*)d_ws;
  f16* featsH = (f16*)(ws);                 // 16384*192*2 = 6291456
  f16* W1s    = (f16*)(ws + 6291456);       // 6*256*32*2  = 98304
  f16* W2s    = (f16*)(ws + 6389760);       // 8*256*32*2  = 131072
  f16* Wos    = (f16*)(ws + 6520832);       // 8*256*32*2  = 131072
  f16* Wf1s   = (f16*)(ws + 6651904);       // 8*512*32*2  = 262144
  f16* Wf2s   = (f16*)(ws + 6914048);       // 16*256*32*2 = 262144

  prep_ws<<<192, 256, 0, stream>>>(W1,  W1s,  161, 256, 6  * 256 * 32);
  prep_ws<<<256, 256, 0, stream>>>(W2,  W2s,  256, 256, 8  * 256 * 32);
  prep_ws<<<256, 256, 0, stream>>>(Wo,  Wos,  256, 256, 8  * 256 * 32);
  prep_ws<<<512, 256, 0, stream>>>(Wf1, Wf1s, 256, 512, 8  * 512 * 32);
  prep_ws<<<512, 256, 0, stream>>>(Wf2, Wf2s, 512, 256, 16 * 256 * 32);
  feat_kernel<<<256, 64, 0, stream>>>(x, z, tables, res, freqs, featsH);

  (void)hipFuncSetAttribute((const void*)fractal_main,
                            hipFuncAttributeMaxDynamicSharedMemorySize, 98304);
  fractal_main<<<256, 512, 98304, stream>>>(featsH, W1s, W2s, Wos, Wf1s, Wf2s,
                                            b1, b2, bf1, bf2, bo, out);
}

// Round 4
// 1864.556 us; speedup vs baseline: 1.2866x; 1.1905x over previous
//
#include <hip/hip_runtime.h>
#include <hip/hip_fp16.h>
#include <math.h>
#include <stdint.h>

typedef _Float16 f16;
typedef _Float16 h8 __attribute__((ext_vector_type(8)));
typedef float f4 __attribute__((ext_vector_type(4)));

#define TSTEPS 48

#define MFMA(a,b,c) __builtin_amdgcn_mfma_f32_16x16x32_f16((a),(b),(c),0,0,0)

// branch-free gelu via A&S 7.1.26 erf approx (max abs err 1.5e-7 << f16 rounding)
__device__ __forceinline__ float gelu_f(float x) {
  float ax = fabsf(x) * 0.7071067811865475f;
  float t = __builtin_amdgcn_rcpf(1.0f + 0.3275911f * ax);
  float poly = t * (0.254829592f + t * (-0.284496736f + t * (1.421413741f +
               t * (-1.453152027f + t * 1.061405429f))));
  float e = exp2f(-ax * ax * 1.4426950408889634f);
  float er = copysignf(1.0f - poly * e, x);
  return 0.5f * x * (1.0f + er);
}

// tanh = 1 - 2/(e^{2x}+1); exp2 overflow/underflow gives correct +-1 limits
__device__ __forceinline__ float tanh_f(float x) {
  float e = exp2f(x * 2.885390081777927f);   // e^{2x}
  return 1.0f - 2.0f * __builtin_amdgcn_rcpf(e + 1.0f);
}

// ---------------- weight prep: k-slice stream  dst[(kk*N+n)*32+w] = src[(kk*32+w)*N+n]
__global__ void prep_ws(const float* __restrict__ src, f16* __restrict__ dst,
                        int Kreal, int N, int total) {
  int idx = blockIdx.x * 256 + threadIdx.x;
  if (idx >= total) return;
  int w = idx & 31;
  int n = (idx >> 5) % N;
  int kk = idx / (N * 32);
  int k = kk * 32 + w;
  dst[idx] = (f16)((k < Kreal) ? src[k * N + n] : 0.f);
}

// ---------------- feature kernel: fourier + hashgrid + z -> fp16 [B][192] ----
__global__ void feat_kernel(const float* __restrict__ x, const float* __restrict__ z,
                            const float* __restrict__ tables, const int* __restrict__ res,
                            const float* __restrict__ freqs, f16* __restrict__ featsH) {
  __shared__ f16 rowbuf[64][194];
  const int t = threadIdx.x;        // 64 threads
  const int b = blockIdx.x;
  const int i = b * 64 + t;

  float xv = x[i];
  float xn = fminf(fmaxf(xv, 0.f), 1.f);
  f16* dst = rowbuf[t];
  dst[0] = (f16)xn;
  float w2pi = 6.283185307179586f * xn;
  #pragma unroll
  for (int k = 0; k < 32; ++k) {
    float a = w2pi * freqs[k];
    float s, c;
    sincosf(a, &s, &c);
    dst[1 + k]  = (f16)s;
    dst[33 + k] = (f16)c;
  }
  #pragma unroll
  for (int l = 0; l < 8; ++l) {
    int R = res[l];
    int Rm1 = R - 1;
    float tt = xn * (float)Rm1;
    int i0 = (int)tt;
    int i1 = min(i0 + 1, Rm1);
    float w = tt - (float)i0;
    uint32_t lt = (uint32_t)(l * 19349663);
    uint32_t h0 = (((uint32_t)i0 * 73856093u) ^ lt) & 16383u;
    uint32_t h1 = (((uint32_t)i1 * 73856093u) ^ lt) & 16383u;
    const float* e0 = tables + ((size_t)l * 16384 + h0) * 8;
    const float* e1 = tables + ((size_t)l * 16384 + h1) * 8;
    #pragma unroll
    for (int e = 0; e < 8; ++e) {
      float v = e0[e] * (1.f - w) + e1[e] * w;
      dst[65 + l * 8 + e] = (f16)v;
    }
  }
  #pragma unroll
  for (int j = 0; j < 32; ++j) dst[129 + j] = (f16)z[(size_t)i * 32 + j];
  #pragma unroll
  for (int j = 161; j < 192; ++j) dst[j] = (f16)0.f;

  __syncthreads();
  uint32_t* dg = (uint32_t*)(featsH + (size_t)b * 64 * 192);
  for (int idx = t; idx < 64 * 96; idx += 64) {
    int row = idx / 96, o = idx - row * 96;
    dg[idx] = ((const uint32_t*)&rowbuf[row][0])[o];
  }
}

// ---------------- main fused kernel ----------------
// 256 blocks x 1024 threads (16 waves) = 4 waves/SIMD for latency hiding.
// Block owns 64 rows. Wave-grid 1M x 16N:
//   GEMM1 (N=512): wave wn covers cols [32*wn, +32)  (2 n-frags)
//   GEMM2/layers (N=256): wave wn covers cols [16*wn, +16) (1 n-frag)
// LDS: hB [0,32K) fp16 h tile [64][256] stride 512B (XOR-swizzled)
//      uB [32K,96K) fp16 u tile [64][512] stride 1024B (feats staging reuses)
// B-operands: direct global loads from k-slice streams (contiguous 1KB/wave/frag),
// distance-2 register prefetch inside each GEMM phase.
__global__ __launch_bounds__(1024, 4) void fractal_main(
    const f16* __restrict__ featsH,
    const f16* __restrict__ W1s, const f16* __restrict__ W2s,
    const f16* __restrict__ Wos,
    const f16* __restrict__ Wf1s, const f16* __restrict__ Wf2s,
    const float* __restrict__ b1, const float* __restrict__ b2,
    const float* __restrict__ bf1, const float* __restrict__ bf2,
    const float* __restrict__ bo,
    float* __restrict__ out) {
  extern __shared__ char smem[];
  char* hB = smem;
  char* uB = smem + 32768;

  const int tid = threadIdx.x;
  const int wn  = tid >> 6;          // 0..15
  const int ln  = tid & 63;
  const int r   = ln & 15;
  const int g   = ln >> 4;
  const int sw  = (r & 7) << 4;
  const int g16 = g * 16;
  const int row0 = blockIdx.x * 64;

  const int cH = 16 * wn + r;        // this wave's HID-space column
  float b1r = b1[cH], b2r = b2[cH], bf2r = bf2[cH], bor = bo[cH];
  float bf1r[2];
  #pragma unroll
  for (int nf = 0; nf < 2; ++nf) bf1r[nf] = bf1[32 * wn + 16 * nf + r];

  // ---- stage feats tile into uB (swizzled, row stride 384B) ----
  {
    const char* src = (const char*)featsH + (size_t)row0 * 384;
    for (int i = tid; i < 6144; i += 1024) {
      int row = i / 96;
      int off = (i - row * 96) * 4;
      uint32_t v = *(const uint32_t*)(src + (size_t)i * 4);
      *(uint32_t*)(uB + row * 384 + (off ^ ((row & 7) << 4))) = v;
    }
  }
  __syncthreads();

  f4 m[4];                           // master h (f32), rows 16*mf+g*4+j, col cH
  const f4 zf = {0.f, 0.f, 0.f, 0.f};

  // ---- layer 1: feats @ W1 ----
  {
    f4 acc[4];
    #pragma unroll
    for (int mf = 0; mf < 4; ++mf) acc[mf] = zf;
    #pragma unroll
    for (int kk = 0; kk < 6; ++kk) {
      h8 a[4];
      h8 bb = *(const h8*)(W1s + ((kk * 256 + cH) << 5) + g * 8);
      #pragma unroll
      for (int mf = 0; mf < 4; ++mf)
        a[mf] = *(const h8*)(uB + (16 * mf + r) * 384 + ((kk * 64 + g16) ^ sw));
      #pragma unroll
      for (int mf = 0; mf < 4; ++mf) acc[mf] = MFMA(a[mf], bb, acc[mf]);
    }
    #pragma unroll
    for (int mf = 0; mf < 4; ++mf)
      #pragma unroll
      for (int j = 0; j < 4; ++j)
        m[mf][j] = gelu_f(acc[mf][j] + b1r);
  }
  #pragma unroll
  for (int mf = 0; mf < 4; ++mf)
    #pragma unroll
    for (int j = 0; j < 4; ++j) {
      int row = 16 * mf + g * 4 + j;
      *(f16*)(hB + row * 512 + ((cH * 2) ^ ((row & 7) << 4))) = (f16)m[mf][j];
    }
  __syncthreads();

  // ---- layer 2: h @ W2 ----
  {
    f4 acc[4];
    #pragma unroll
    for (int mf = 0; mf < 4; ++mf) acc[mf] = zf;
    #pragma unroll
    for (int kk = 0; kk < 8; ++kk) {
      h8 a[4];
      h8 bb = *(const h8*)(W2s + ((kk * 256 + cH) << 5) + g * 8);
      #pragma unroll
      for (int mf = 0; mf < 4; ++mf)
        a[mf] = *(const h8*)(hB + (16 * mf + r) * 512 + ((kk * 64 + g16) ^ sw));
      #pragma unroll
      for (int mf = 0; mf < 4; ++mf) acc[mf] = MFMA(a[mf], bb, acc[mf]);
    }
    #pragma unroll
    for (int mf = 0; mf < 4; ++mf)
      #pragma unroll
      for (int j = 0; j < 4; ++j)
        m[mf][j] = gelu_f(acc[mf][j] + b2r);
  }
  __syncthreads();   // all waves done reading old hB
  #pragma unroll
  for (int mf = 0; mf < 4; ++mf)
    #pragma unroll
    for (int j = 0; j < 4; ++j) {
      int row = 16 * mf + g * 4 + j;
      *(f16*)(hB + row * 512 + ((cH * 2) ^ ((row & 7) << 4))) = (f16)m[mf][j];
    }
  __syncthreads();

  // ---- 48 fractal steps, 2 barriers per step ----
  for (int t = 0; t < TSTEPS; ++t) {
    // GEMM1: u = h @ Wf1 (N=512), wave cols [32*wn,+32), distance-2 B prefetch
    f4 a1[4][2];
    #pragma unroll
    for (int mf = 0; mf < 4; ++mf)
      #pragma unroll
      for (int nf = 0; nf < 2; ++nf) a1[mf][nf] = zf;
    {
      h8 pb[3][2];
      #pragma unroll
      for (int nf = 0; nf < 2; ++nf) {
        pb[0][nf] = *(const h8*)(Wf1s + ((0 * 512 + 32 * wn + 16 * nf + r) << 5) + g * 8);
        pb[1][nf] = *(const h8*)(Wf1s + ((1 * 512 + 32 * wn + 16 * nf + r) << 5) + g * 8);
      }
      #pragma unroll
      for (int kk = 0; kk < 8; ++kk) {
        if (kk + 2 < 8) {
          #pragma unroll
          for (int nf = 0; nf < 2; ++nf)
            pb[(kk + 2) % 3][nf] =
              *(const h8*)(Wf1s + (((kk + 2) * 512 + 32 * wn + 16 * nf + r) << 5) + g * 8);
        }
        h8 a[4];
        #pragma unroll
        for (int mf = 0; mf < 4; ++mf)
          a[mf] = *(const h8*)(hB + (16 * mf + r) * 512 + ((kk * 64 + g16) ^ sw));
        #pragma unroll
        for (int mf = 0; mf < 4; ++mf)
          #pragma unroll
          for (int nf = 0; nf < 2; ++nf)
            a1[mf][nf] = MFMA(a[mf], pb[kk % 3][nf], a1[mf][nf]);
      }
    }
    // epilogue: gelu -> uB
    #pragma unroll
    for (int mf = 0; mf < 4; ++mf)
      #pragma unroll
      for (int nf = 0; nf < 2; ++nf)
        #pragma unroll
        for (int j = 0; j < 4; ++j) {
          float gv = gelu_f(a1[mf][nf][j] + bf1r[nf]);
          int row = 16 * mf + g * 4 + j;
          int col = 32 * wn + 16 * nf + r;
          *(f16*)(uB + row * 1024 + ((col * 2) ^ ((row & 7) << 4))) = (f16)gv;
        }
    __syncthreads();

    // GEMM2: h' = tanh(u @ Wf2) (N=256, K=512), wave col set [16*wn,+16)
    f4 a2[4];
    #pragma unroll
    for (int mf = 0; mf < 4; ++mf) a2[mf] = zf;
    {
      h8 qb[3];
      qb[0] = *(const h8*)(Wf2s + ((0 * 256 + cH) << 5) + g * 8);
      qb[1] = *(const h8*)(Wf2s + ((1 * 256 + cH) << 5) + g * 8);
      #pragma unroll
      for (int kk = 0; kk < 16; ++kk) {
        if (kk + 2 < 16)
          qb[(kk + 2) % 3] = *(const h8*)(Wf2s + (((kk + 2) * 256 + cH) << 5) + g * 8);
        h8 a[4];
        #pragma unroll
        for (int mf = 0; mf < 4; ++mf)
          a[mf] = *(const h8*)(uB + (16 * mf + r) * 1024 + ((kk * 64 + g16) ^ sw));
        #pragma unroll
        for (int mf = 0; mf < 4; ++mf)
          a2[mf] = MFMA(a[mf], qb[kk % 3], a2[mf]);
      }
    }
    // epilogue: tanh, mix, write hB
    #pragma unroll
    for (int mf = 0; mf < 4; ++mf)
      #pragma unroll
      for (int j = 0; j < 4; ++j) {
        float u = tanh_f(a2[mf][j] + bf2r);
        float hn = 0.5f * (m[mf][j] + u);
        m[mf][j] = hn;
        int row = 16 * mf + g * 4 + j;
        *(f16*)(hB + row * 512 + ((cH * 2) ^ ((row & 7) << 4))) = (f16)hn;
      }
    __syncthreads();
  }

  // ---- final: out = h @ Wo + bo ----
  {
    f4 acc[4];
    #pragma unroll
    for (int mf = 0; mf < 4; ++mf) acc[mf] = zf;
    #pragma unroll
    for (int kk = 0; kk < 8; ++kk) {
      h8 a[4];
      h8 bb = *(const h8*)(Wos + ((kk * 256 + cH) << 5) + g * 8);
      #pragma unroll
      for (int mf = 0; mf < 4; ++mf)
        a[mf] = *(const h8*)(hB + (16 * mf + r) * 512 + ((kk * 64 + g16) ^ sw));
      #pragma unroll
      for (int mf = 0; mf < 4; ++mf) acc[mf] = MFMA(a[mf], bb, acc[mf]);
    }
    #pragma unroll
    for (int mf = 0; mf < 4; ++mf)
      #pragma unroll
      for (int j = 0; j < 4; ++j) {
        int row = row0 + 16 * mf + g * 4 + j;
        out[(size_t)row * 256 + cH] = acc[mf][j] + bor;
      }
  }
}

// ---------------- host launch ----------------
extern "C" void kernel_launch(void* const* d_in, const int* in_sizes, int n_in,
                              void* d_out, int out_size, void* d_ws, size_t ws_size,
                              hipStream_t stream) {
  const float* x      = (const float*)d_in[0];
  const float* z      = (const float*)d_in[1];
  const float* tables = (const float*)d_in[2];
  const float* W1     = (const float*)d_in[3];
  const float* b1     = (const float*)d_in[4];
  const float* W2     = (const float*)d_in[5];
  const float* b2     = (const float*)d_in[6];
  const float* Wf1    = (const float*)d_in[7];
  const float* bf1    = (const float*)d_in[8];
  const float* Wf2    = (const float*)d_in[9];
  const float* bf2    = (const float*)d_in[10];
  const float* Wo     = (const float*)d_in[11];
  const float* bo     = (const float*)d_in[12];
  const int*   res    = (const int*)d_in[13];
  const float* freqs  = (const float*)d_in[14];
  float* out = (float*)d_out;

  char* ws = (char*)d_ws;
  f16* featsH = (f16*)(ws);                 // 16384*192*2 = 6291456
  f16* W1s    = (f16*)(ws + 6291456);       // 6*256*32*2  = 98304
  f16* W2s    = (f16*)(ws + 6389760);       // 8*256*32*2  = 131072
  f16* Wos    = (f16*)(ws + 6520832);       // 8*256*32*2  = 131072
  f16* Wf1s   = (f16*)(ws + 6651904);       // 8*512*32*2  = 262144
  f16* Wf2s   = (f16*)(ws + 6914048);       // 16*256*32*2 = 262144

  prep_ws<<<192, 256, 0, stream>>>(W1,  W1s,  161, 256, 6  * 256 * 32);
  prep_ws<<<256, 256, 0, stream>>>(W2,  W2s,  256, 256, 8  * 256 * 32);
  prep_ws<<<256, 256, 0, stream>>>(Wo,  Wos,  256, 256, 8  * 256 * 32);
  prep_ws<<<512, 256, 0, stream>>>(Wf1, Wf1s, 256, 512, 8  * 512 * 32);
  prep_ws<<<512, 256, 0, stream>>>(Wf2, Wf2s, 512, 256, 16 * 256 * 32);
  feat_kernel<<<256, 64, 0, stream>>>(x, z, tables, res, freqs, featsH);

  (void)hipFuncSetAttribute((const void*)fractal_main,
                            hipFuncAttributeMaxDynamicSharedMemorySize, 98304);
  fractal_main<<<256, 1024, 98304, stream>>>(featsH, W1s, W2s, Wos, Wf1s, Wf2s,
                                             b1, b2, bf1, bf2, bo, out);
}